// Round 4
// baseline (418.395 us; speedup 1.0000x reference)
//
#include <hip/hip_runtime.h>
#include <hip/hip_bf16.h>
#include <math.h>

#define D 256

typedef short s16x8 __attribute__((ext_vector_type(8)));
typedef float f32x4 __attribute__((ext_vector_type(4)));

__device__ __forceinline__ unsigned short f2bf(float f) {
    unsigned int u = __builtin_bit_cast(unsigned int, f);
    unsigned int r = (u + 0x7fffu + ((u >> 16) & 1u)) >> 16;  // RNE
    return (unsigned short)r;
}
__device__ __forceinline__ float bf2f(unsigned short s) {
    unsigned int u = ((unsigned int)s) << 16;
    return __builtin_bit_cast(float, u);
}

// async 16B global -> LDS (wave-uniform LDS base + lane*16)
__device__ __forceinline__ void gl_lds16(const void* g, void* l) {
    __builtin_amdgcn_global_load_lds(
        (const __attribute__((address_space(1))) void*)g,
        (__attribute__((address_space(3))) void*)l, 16, 0, 0);
}

// Wsw[((kt*16 + nt)*64 + lane)*8 + j] = bf16(W[kt*32 + (lane>>4)*8 + j][nt*16 + (lane&15)])
__global__ void swizzle_w(const float* __restrict__ W1, const float* __restrict__ Wr,
                          unsigned short* __restrict__ W1sw, unsigned short* __restrict__ Wrsw) {
    int idx = blockIdx.x * blockDim.x + threadIdx.x;  // 0 .. 2*65536-1
    int m = idx >> 16;
    int t = idx & 65535;
    const float* src = m ? Wr : W1;
    unsigned short* dst = m ? Wrsw : W1sw;
    int j = t & 7, lane = (t >> 3) & 63, nt = (t >> 9) & 15, kt = t >> 13;
    int k = kt * 32 + (lane >> 4) * 8 + j;
    int n = nt * 16 + (lane & 15);
    dst[t] = f2bf(src[k * D + n]);
}

__global__ void build_row_ptr(const int* __restrict__ rows, int* __restrict__ rp, int N, int E) {
    int r = blockIdx.x * blockDim.x + threadIdx.x;
    if (r > N) return;
    int lo = 0, hi = E;
    while (lo < hi) {
        int mid = (lo + hi) >> 1;
        if (rows[mid] < r) lo = mid + 1; else hi = mid;
    }
    rp[r] = lo;
}

// ---------------- GEMM kernels ----------------
// Block = 512 thr = 8 waves. Wave w owns cols [w*32, w*32+32).
// LDS A layout = frag order: lA[((mt*8+kt)*64 + ll)*8 + j], mt in {0,1};
// element (row_in_tile rt, k): mt=rt>>4, rl=rt&15, kt=k>>5, qd=(k>>3)&3, j=k&7
//   -> lA[((mt*8+kt)*64 + qd*16 + rl)*8 + j]

__device__ __forceinline__ void stage_a_frag(const float* __restrict__ Xrow, int k0,
                                             unsigned short* __restrict__ lA, int fgi,
                                             s16x8* sf_out) {
    float4 f0 = *(const float4*)(Xrow + k0);
    float4 f1 = *(const float4*)(Xrow + k0 + 4);
    s16x8 sf;
    sf[0] = (short)f2bf(f0.x); sf[1] = (short)f2bf(f0.y);
    sf[2] = (short)f2bf(f0.z); sf[3] = (short)f2bf(f0.w);
    sf[4] = (short)f2bf(f1.x); sf[5] = (short)f2bf(f1.y);
    sf[6] = (short)f2bf(f1.z); sf[7] = (short)f2bf(f1.w);
    *(s16x8*)(lA + (size_t)fgi * 8) = sf;
    *sf_out = sf;
}

// gemm1: h = bf16(X @ W1); also emits Xbf = bf16(X) when xbf != nullptr.
__global__ __launch_bounds__(512) void gemm1_b(const float* __restrict__ X,
                                               const unsigned short* __restrict__ Wsw,
                                               unsigned short* __restrict__ h,
                                               unsigned short* __restrict__ xbf,
                                               int N, int numTiles) {
    __shared__ unsigned short lA[2 * 8 * 64 * 8];  // 16 KB
    int t = threadIdx.x;
    int lane = t & 63;
    int wave = t >> 6;
    int quad = lane >> 4;

    s16x8 bfr[2][8];
#pragma unroll
    for (int ntl = 0; ntl < 2; ntl++) {
        int nt = wave * 2 + ntl;
#pragma unroll
        for (int kt = 0; kt < 8; kt++)
            bfr[ntl][kt] = *(const s16x8*)(Wsw + ((size_t)((kt * 16 + nt) * 64 + lane)) * 8);
    }

    for (int tile = blockIdx.x; tile < numTiles; tile += gridDim.x) {
#pragma unroll
        for (int q = 0; q < 2; q++) {
            int fgi = q * 512 + t;
            int mt = fgi >> 9, kt = (fgi >> 6) & 7, ll = fgi & 63;
            int rl = ll & 15, qd = ll >> 4;
            int grow = tile * 32 + mt * 16 + rl;
            if (grow >= N) grow = N - 1;
            int k0 = kt * 32 + qd * 8;
            s16x8 sf;
            stage_a_frag(X + (size_t)grow * D, k0, lA, fgi, &sf);
            if (xbf) *(s16x8*)(xbf + (size_t)grow * D + k0) = sf;
        }
        __syncthreads();

        f32x4 acc[2][2];
#pragma unroll
        for (int mt = 0; mt < 2; mt++)
#pragma unroll
            for (int ntl = 0; ntl < 2; ntl++) acc[mt][ntl] = (f32x4){0.f, 0.f, 0.f, 0.f};

#pragma unroll
        for (int mt = 0; mt < 2; mt++)
#pragma unroll
            for (int kt = 0; kt < 8; kt++) {
                s16x8 a = *(const s16x8*)(lA + (size_t)(((mt * 8 + kt) * 64 + lane)) * 8);
                acc[mt][0] = __builtin_amdgcn_mfma_f32_16x16x32_bf16(a, bfr[0][kt], acc[mt][0], 0, 0, 0);
                acc[mt][1] = __builtin_amdgcn_mfma_f32_16x16x32_bf16(a, bfr[1][kt], acc[mt][1], 0, 0, 0);
            }

#pragma unroll
        for (int mt = 0; mt < 2; mt++)
#pragma unroll
            for (int ntl = 0; ntl < 2; ntl++) {
                int col = (wave * 2 + ntl) * 16 + (lane & 15);
#pragma unroll
                for (int r = 0; r < 4; r++) {
                    int grow = tile * 32 + mt * 16 + quad * 4 + r;
                    if (grow < N) h[(size_t)grow * D + col] = f2bf(acc[mt][ntl][r]);
                }
            }
        __syncthreads();
    }
}

// gemm2 fast path: A staged from Xbf via async global_load_lds (width 16).
__global__ __launch_bounds__(512) void gemm2_b(const unsigned short* __restrict__ Xbf,
                                               const int* __restrict__ perm,
                                               const unsigned short* __restrict__ Wsw,
                                               const float* __restrict__ br,
                                               const unsigned short* __restrict__ agg,
                                               float* __restrict__ out,
                                               int N, int numTiles) {
    __shared__ unsigned short lA[2 * 8 * 64 * 8];  // 16 KB
    int t = threadIdx.x;
    int lane = t & 63;
    int wave = t >> 6;
    int quad = lane >> 4;

    s16x8 bfr[2][8];
#pragma unroll
    for (int ntl = 0; ntl < 2; ntl++) {
        int nt = wave * 2 + ntl;
#pragma unroll
        for (int kt = 0; kt < 8; kt++)
            bfr[ntl][kt] = *(const s16x8*)(Wsw + ((size_t)((kt * 16 + nt) * 64 + lane)) * 8);
    }

    for (int tile = blockIdx.x; tile < numTiles; tile += gridDim.x) {
        // async stage: wave w handles (mt=q, kt=w); per-lane gathered source, frag-order dest
#pragma unroll
        for (int q = 0; q < 2; q++) {
            int mt = q, kt = wave;
            int grow = tile * 32 + mt * 16 + (lane & 15);
            if (grow >= N) grow = N - 1;
            int pr = perm[grow];
            int col = kt * 32 + (lane >> 4) * 8;
            gl_lds16(Xbf + (size_t)pr * D + col, &lA[(size_t)((mt * 8 + kt) * 64) * 8]);
        }
        __syncthreads();

        f32x4 acc[2][2];
#pragma unroll
        for (int mt = 0; mt < 2; mt++)
#pragma unroll
            for (int ntl = 0; ntl < 2; ntl++) acc[mt][ntl] = (f32x4){0.f, 0.f, 0.f, 0.f};

#pragma unroll
        for (int mt = 0; mt < 2; mt++)
#pragma unroll
            for (int kt = 0; kt < 8; kt++) {
                s16x8 a = *(const s16x8*)(lA + (size_t)(((mt * 8 + kt) * 64 + lane)) * 8);
                acc[mt][0] = __builtin_amdgcn_mfma_f32_16x16x32_bf16(a, bfr[0][kt], acc[mt][0], 0, 0, 0);
                acc[mt][1] = __builtin_amdgcn_mfma_f32_16x16x32_bf16(a, bfr[1][kt], acc[mt][1], 0, 0, 0);
            }

        // epilogue: left = lA (bf16 of X[perm[row]])
#pragma unroll
        for (int mt = 0; mt < 2; mt++) {
#pragma unroll
            for (int ntl = 0; ntl < 2; ntl++) {
                int col = (wave * 2 + ntl) * 16 + (lane & 15);
                float b = br[col];
                int kt2 = col >> 5, qd2 = (col >> 3) & 3, j2 = col & 7;
#pragma unroll
                for (int r = 0; r < 4; r++) {
                    int rt = mt * 16 + quad * 4 + r;
                    int grow = tile * 32 + rt;
                    if (grow < N) {
                        float pre = acc[mt][ntl][r] + b;
                        float gate = 1.f / (1.f + __expf(-pre));
                        float gcn = bf2f(agg[(size_t)grow * D + col]);
                        float left = bf2f(lA[(size_t)(((mt * 8 + kt2) * 64 + qd2 * 16 + (rt & 15))) * 8 + j2]);
                        out[(size_t)grow * D + col] = gate * gcn + (1.f - gate) * left;
                    }
                }
            }
        }
        __syncthreads();
    }
}

// gemm2 fallback (ws too small for Xbf): stage from fp32 X with convert.
__global__ __launch_bounds__(512) void gemm2_fb(const float* __restrict__ X,
                                                const int* __restrict__ perm,
                                                const unsigned short* __restrict__ Wsw,
                                                const float* __restrict__ br,
                                                const unsigned short* __restrict__ agg,
                                                float* __restrict__ out,
                                                int N, int numTiles) {
    __shared__ unsigned short lA[2 * 8 * 64 * 8];
    int t = threadIdx.x;
    int lane = t & 63;
    int wave = t >> 6;
    int quad = lane >> 4;

    s16x8 bfr[2][8];
#pragma unroll
    for (int ntl = 0; ntl < 2; ntl++) {
        int nt = wave * 2 + ntl;
#pragma unroll
        for (int kt = 0; kt < 8; kt++)
            bfr[ntl][kt] = *(const s16x8*)(Wsw + ((size_t)((kt * 16 + nt) * 64 + lane)) * 8);
    }

    for (int tile = blockIdx.x; tile < numTiles; tile += gridDim.x) {
#pragma unroll
        for (int q = 0; q < 2; q++) {
            int fgi = q * 512 + t;
            int mt = fgi >> 9, kt = (fgi >> 6) & 7, ll = fgi & 63;
            int rl = ll & 15, qd = ll >> 4;
            int grow = tile * 32 + mt * 16 + rl;
            if (grow >= N) grow = N - 1;
            int pr = perm[grow];
            s16x8 sf;
            stage_a_frag(X + (size_t)pr * D, kt * 32 + qd * 8, lA, fgi, &sf);
        }
        __syncthreads();

        f32x4 acc[2][2];
#pragma unroll
        for (int mt = 0; mt < 2; mt++)
#pragma unroll
            for (int ntl = 0; ntl < 2; ntl++) acc[mt][ntl] = (f32x4){0.f, 0.f, 0.f, 0.f};

#pragma unroll
        for (int mt = 0; mt < 2; mt++)
#pragma unroll
            for (int kt = 0; kt < 8; kt++) {
                s16x8 a = *(const s16x8*)(lA + (size_t)(((mt * 8 + kt) * 64 + lane)) * 8);
                acc[mt][0] = __builtin_amdgcn_mfma_f32_16x16x32_bf16(a, bfr[0][kt], acc[mt][0], 0, 0, 0);
                acc[mt][1] = __builtin_amdgcn_mfma_f32_16x16x32_bf16(a, bfr[1][kt], acc[mt][1], 0, 0, 0);
            }

#pragma unroll
        for (int mt = 0; mt < 2; mt++) {
#pragma unroll
            for (int ntl = 0; ntl < 2; ntl++) {
                int col = (wave * 2 + ntl) * 16 + (lane & 15);
                float b = br[col];
                int kt2 = col >> 5, qd2 = (col >> 3) & 3, j2 = col & 7;
#pragma unroll
                for (int r = 0; r < 4; r++) {
                    int rt = mt * 16 + quad * 4 + r;
                    int grow = tile * 32 + rt;
                    if (grow < N) {
                        float pre = acc[mt][ntl][r] + b;
                        float gate = 1.f / (1.f + __expf(-pre));
                        float gcn = bf2f(agg[(size_t)grow * D + col]);
                        float left = bf2f(lA[(size_t)(((mt * 8 + kt2) * 64 + qd2 * 16 + (rt & 15))) * 8 + j2]);
                        out[(size_t)grow * D + col] = gate * gcn + (1.f - gate) * left;
                    }
                }
            }
        }
        __syncthreads();
    }
}

// ---------------- Scatter: wave-per-row, 16-deep gather pipeline ----------------
__device__ __forceinline__ void acc4(float4& a, uint2 u, float v) {
    float x0 = __builtin_bit_cast(float, u.x << 16);
    float x1 = __builtin_bit_cast(float, u.x & 0xffff0000u);
    float x2 = __builtin_bit_cast(float, u.y << 16);
    float x3 = __builtin_bit_cast(float, u.y & 0xffff0000u);
    a.x += v * x0; a.y += v * x1; a.z += v * x2; a.w += v * x3;
}

__global__ __launch_bounds__(256) void scatter2(const uint2* __restrict__ hp,
                                                const int* __restrict__ rp,
                                                const int* __restrict__ cols,
                                                const float* __restrict__ vals,
                                                uint2* __restrict__ aggp,
                                                int N, int E) {
    int lane = threadIdx.x & 63;
    int wave = threadIdx.x >> 6;
    int row = blockIdx.x * 4 + wave;
    if (row >= N) return;
    int start = rp[row], end = rp[row + 1];

    float4 a = {0.f, 0.f, 0.f, 0.f};
    for (int base = start; base < end; base += 64) {
        int ii = base + lane;
        int iic = ii < E ? ii : E - 1;
        int cl = cols[iic];
        int vbits = __builtin_bit_cast(int, vals[iic]);
        int n = end - base; if (n > 64) n = 64;
        int i = 0;
        for (; i + 16 <= n; i += 16) {
            uint2 u[16]; float vv[16];
#pragma unroll
            for (int k = 0; k < 16; k++) {
                int c = __builtin_amdgcn_readlane(cl, i + k);
                vv[k] = __builtin_bit_cast(float, __builtin_amdgcn_readlane(vbits, i + k));
                u[k] = hp[(size_t)c * 64 + lane];
            }
#pragma unroll
            for (int k = 0; k < 16; k++) acc4(a, u[k], vv[k]);
        }
        for (; i + 8 <= n; i += 8) {
            uint2 u[8]; float vv[8];
#pragma unroll
            for (int k = 0; k < 8; k++) {
                int c = __builtin_amdgcn_readlane(cl, i + k);
                vv[k] = __builtin_bit_cast(float, __builtin_amdgcn_readlane(vbits, i + k));
                u[k] = hp[(size_t)c * 64 + lane];
            }
#pragma unroll
            for (int k = 0; k < 8; k++) acc4(a, u[k], vv[k]);
        }
        for (; i < n; i++) {
            int c = __builtin_amdgcn_readlane(cl, i);
            float v = __builtin_bit_cast(float, __builtin_amdgcn_readlane(vbits, i));
            uint2 u = hp[(size_t)c * 64 + lane];
            acc4(a, u, v);
        }
    }
    a.x = fmaxf(a.x, 0.f); a.y = fmaxf(a.y, 0.f);
    a.z = fmaxf(a.z, 0.f); a.w = fmaxf(a.w, 0.f);
    uint2 o;
    o.x = (unsigned int)f2bf(a.x) | ((unsigned int)f2bf(a.y) << 16);
    o.y = (unsigned int)f2bf(a.z) | ((unsigned int)f2bf(a.w) << 16);
    aggp[(size_t)row * 64 + lane] = o;
}

extern "C" void kernel_launch(void* const* d_in, const int* in_sizes, int n_in,
                              void* d_out, int out_size, void* d_ws, size_t ws_size,
                              hipStream_t stream) {
    const float* right = (const float*)d_in[0];
    const float* W1    = (const float*)d_in[1];
    const float* Wr    = (const float*)d_in[2];
    const float* br    = (const float*)d_in[3];
    const float* evals = (const float*)d_in[4];
    const int*   erows = (const int*)d_in[5];
    const int*   ecols = (const int*)d_in[6];
    const int*   perm  = (const int*)d_in[7];
    int N = in_sizes[7];
    int E = in_sizes[4];
    float* out = (float*)d_out;

    char* ws = (char*)d_ws;
    unsigned short* W1sw = (unsigned short*)ws;
    unsigned short* Wrsw = W1sw + D * D;
    int* rp = (int*)(ws + (size_t)2 * D * D * 2);
    size_t off = (size_t)2 * D * D * 2 + 4 * (size_t)(N + 1);
    off = (off + 255) & ~(size_t)255;
    unsigned short* h = (unsigned short*)(ws + off);
    unsigned short* agg = h + (size_t)N * D;
    unsigned short* xbf = agg + (size_t)N * D;
    bool fast = ws_size >= off + 3 * (size_t)N * D * 2;

    int numTiles = (N + 31) / 32;

    swizzle_w<<<512, 256, 0, stream>>>(W1, Wr, W1sw, Wrsw);
    build_row_ptr<<<(N + 256) / 256, 256, 0, stream>>>(erows, rp, N, E);
    gemm1_b<<<numTiles, 512, 0, stream>>>(right, W1sw, h, fast ? xbf : nullptr, N, numTiles);
    scatter2<<<(N + 3) / 4, 256, 0, stream>>>((const uint2*)h, rp, ecols, evals,
                                              (uint2*)agg, N, E);
    if (fast)
        gemm2_b<<<numTiles, 512, 0, stream>>>(xbf, perm, Wrsw, br, agg, out, N, numTiles);
    else
        gemm2_fb<<<numTiles, 512, 0, stream>>>(right, perm, Wrsw, br, agg, out, N, numTiles);
}